// Round 10
// baseline (291.559 us; speedup 1.0000x reference)
//
#include <hip/hip_runtime.h>

// GCN(3 layers) + MLP(4 layers), N=50000, E=800000, out = N x 8 bf16.
// NOTE: do NOT include <hip/hip_bf16.h> — breaks this harness's build.
// Manual bf16 ushort ops. Dtype runtime-detection: flagI/flagF.
//
// R24: 16-edge chunks + dinv-pre-scaled rows: 277.7 µs, agmlp 61.2.
// R25: col-per-lane transpose regressed (rows-per-load-INSTRUCTION governs).
// R26: packed f32x2 accum neutral => VALU not binding.
// R27: int8 regressed via spills (unified VGPR+AGPR, ~32 VGPR cap at (1024,8)).
// R28: (1024,4) regressed: occupancy halved, in-flight did not rise.
// R29: 512-thr/8-node blocks regressed: residency fixed but MFMA doubled
//      (16-row tiles, 8 valid) + 2x barriers. DIAGNOSIS CONFIRMED: 1024-thr
//      blocks cap at 2 resident (32-wave/CU); per-block path ~1.9µs.
// R30 (retry — R9 bench failed on GPUAcquisitionTimeout, kernel untested):
//      512 threads, 16 nodes/block, TWO nodes per wave as independent
//      interleaved gather chains. MFMA tiles 16-row all-valid (per-block
//      MFMA = R24), 3125 blocks, 4 resident blocks/CU. 96-wide gathers
//      use 8-edge chunks (reg budget ~50 < 64 cap); 64-wide keeps 16.

#define GN 50000
#define GE 800000
#define NPART 98        // partitions of 512 dst nodes
#define PSLOT 9216      // slab capacity per partition (mean 8163, +11 sigma)
#define CHK 2048        // edges per block in pass 1

typedef __attribute__((ext_vector_type(8))) short bf16x8;
typedef __attribute__((ext_vector_type(4))) float floatx4;
typedef __attribute__((ext_vector_type(2))) float floatx2;
typedef __attribute__((ext_vector_type(4))) unsigned int uintx4;

__device__ __forceinline__ float ar1_b2f(unsigned short h) {
    return __uint_as_float(((unsigned)h) << 16);
}
__device__ __forceinline__ unsigned short ar1_f2b(float f) {
    unsigned u = __float_as_uint(f);
    u = u + 0x7FFFu + ((u >> 16) & 1u);   // round-to-nearest-even
    return (unsigned short)(u >> 16);
}
// unpack one dword (2 packed bf16) -> f32x2 {lo, hi}
__device__ __forceinline__ floatx2 ar1_up2(unsigned w) {
    floatx2 t;
    t[0] = __uint_as_float(w << 16);
    t[1] = __uint_as_float(w & 0xFFFF0000u);
    return t;
}

// wave-parallel detectors (4 loads + butterfly; every wave gets the answer)
__device__ __forceinline__ int ar1_det64(const int* ei) {
    int l = (int)threadIdx.x & 63;
    int nz = 0;
#pragma unroll
    for (int k = 0; k < 4; k++)
        nz += (ei[2 * (l + 64 * k) + 1] != 0) ? 1 : 0;
#pragma unroll
    for (int o = 1; o < 64; o <<= 1)
        nz += __shfl_xor(nz, o, 64);
    return (nz < 8) ? 1 : 0;                 // 1 => int64
}
__device__ __forceinline__ int ar1_detf32(const unsigned short* xw) {
    int l = (int)threadIdx.x & 63;
    int c = 0;
#pragma unroll
    for (int k = 0; k < 4; k++) {
        unsigned short w = xw[2 * (l + 64 * k)];
        int ex = (w >> 7) & 0xFF;
        if (w == 0 || (ex >= 90 && ex <= 150)) c++;
    }
#pragma unroll
    for (int o = 1; o < 64; o <<= 1)
        c += __shfl_xor(c, o, 64);
    return (c > 200) ? 0 : 1;                // 1 => fp32
}

struct PackAll {
    const void* src[7];
    unsigned short* dst[7];
    int K[7], M[7], start[8];
};
struct SmallCvt {
    const void* src[4];   // lb1, lb2, lb3, lb4
    float* dst[4];
    int n[4];
    const void* gb[9];    // b1,g1,be1, b2,g2,be2, b3,g3,be3
    float* ss[6];         // scale1,shift1, ...
};

// merged prep (carries harness kernel name), grid = 391 + 45 + 1 + 1563 = 2000:
//  b<391: edge partition pass (self-detected is64); needs gcur pre-zeroed.
//  b<436: pack 4 MFMA B-fragments each (self-detected flagF).
//  b==436: small cvt + BN fold; zero-rows + dinv[GN]; writes flagI/flagF.
//  b>=437: X -> Xb bf16 conversion (8 elems/thread, streaming).
__global__ __launch_bounds__(256)
void Arthur1_16458314678864_kernel(PackAll pa, SmallCvt sc,
                                   const int* __restrict__ ei,
                                   const unsigned short* __restrict__ xw,
                                   int* flagI, int* flagF,
                                   int* __restrict__ gcur,
                                   unsigned int* __restrict__ pairs,
                                   unsigned short* __restrict__ xb,
                                   unsigned short* __restrict__ bufA,
                                   unsigned short* __restrict__ bufB,
                                   float* __restrict__ dinvp) {
    int b = (int)blockIdx.x;
    int tid = (int)threadIdx.x;
    if (b < 391) {
        __shared__ int cnt[NPART], base[NPART], cur[NPART];
        for (int i = tid; i < NPART; i += 256) { cnt[i] = 0; cur[i] = 0; }
        int is64 = ar1_det64(ei);
        __syncthreads();
        int e0 = b * CHK;
        unsigned pk[8]; int q[8];
#pragma unroll
        for (int k = 0; k < 8; k++) {
            int e = e0 + k * 256 + tid;
            q[k] = -1; pk[k] = 0;
            if (e < GE) {
                int s = is64 ? ei[2 * e] : ei[e];
                int d = is64 ? ei[2 * (GE + e)] : ei[GE + e];
                if ((unsigned)s < (unsigned)GN && (unsigned)d < (unsigned)GN) {
                    int qq = d >> 9;
                    q[k] = qq;
                    pk[k] = (unsigned)s | ((unsigned)(d & 511) << 17);
                    atomicAdd(&cnt[qq], 1);
                }
            }
        }
        __syncthreads();
        for (int i = tid; i < NPART; i += 256)
            base[i] = (cnt[i] > 0) ? atomicAdd(&gcur[i], cnt[i]) : 0;
        __syncthreads();
#pragma unroll
        for (int k = 0; k < 8; k++) {
            if (q[k] >= 0) {
                int r = base[q[k]] + atomicAdd(&cur[q[k]], 1);
                if (r < PSLOT) pairs[(size_t)q[k] * PSLOT + r] = pk[k];
            }
        }
    } else if (b < 436) {
        int f = ar1_detf32(xw);
        int frag_g = (b - 391) * 4 + (tid >> 6);
        if (frag_g >= 178) return;
        int w = 0;
        while (w < 6 && frag_g >= pa.start[w + 1]) w++;
        int frag = frag_g - pa.start[w];
        int K = pa.K[w], M = pa.M[w];
        int lane = tid & 63;
        int nch = K >> 5;
        int t = frag / nch, c = frag - t * nch;
        int n = t * 16 + (lane & 15);
        int k0 = c * 32 + (lane >> 4) * 8;
        unsigned short* o = pa.dst[w] + ((size_t)frag * 64 + lane) * 8;
        for (int j = 0; j < 8; j++) {
            unsigned short v = 0;
            if (n < M) {
                int idx = (k0 + j) * M + n;
                v = f ? ar1_f2b(((const float*)pa.src[w])[idx])
                      : ((const unsigned short*)pa.src[w])[idx];
            }
            o[j] = v;
        }
    } else if (b == 436) {
        int f = ar1_detf32(xw);
        int i64 = ar1_det64(ei);
        if (tid == 0) { flagI[0] = i64; flagF[0] = f; dinvp[GN] = 0.f; }
        // zero pad rows (row GN) for the zero-row gather-padding trick
        if (tid < 96) {
            bufA[(size_t)GN * 96 + tid] = 0;
            bufB[(size_t)GN * 96 + tid] = 0;
        }
        if (tid >= 96 && tid < 160) xb[(size_t)GN * 64 + (tid - 96)] = 0;
        const float C = 0.9999950000374997f;   // 1/sqrt(1+1e-5)
        for (int s = 0; s < 4; s++) {
            for (int i = tid; i < sc.n[s]; i += 256) {
                float v = f ? ((const float*)sc.src[s])[i]
                            : ar1_b2f(((const unsigned short*)sc.src[s])[i]);
                sc.dst[s][i] = v;
            }
        }
        for (int k = 0; k < 3; k++) {
            for (int i = tid; i < 96; i += 256) {
                float bb, g, be;
                if (f) {
                    bb = ((const float*)sc.gb[3 * k + 0])[i];
                    g  = ((const float*)sc.gb[3 * k + 1])[i];
                    be = ((const float*)sc.gb[3 * k + 2])[i];
                } else {
                    bb = ar1_b2f(((const unsigned short*)sc.gb[3 * k + 0])[i]);
                    g  = ar1_b2f(((const unsigned short*)sc.gb[3 * k + 1])[i]);
                    be = ar1_b2f(((const unsigned short*)sc.gb[3 * k + 2])[i]);
                }
                sc.ss[2 * k + 0][i] = C * g;
                sc.ss[2 * k + 1][i] = bb * C * g + be;
            }
        }
    } else {
        // X -> bf16 rows (one cache line per row for the layer-1 gather).
        // (dinv scaling is applied later by ar1_csr once degrees are known.)
        int f = ar1_detf32(xw);
        size_t t = (size_t)(b - 437) * 256 + (size_t)tid;
        size_t i0 = t * 8;
        if (i0 < (size_t)GN * 64) {
            bf16x8 o;
            if (f) {
                const float* xf = (const float*)xw;
                floatx4 a = *((const floatx4*)(xf + i0));
                floatx4 c = *((const floatx4*)(xf + i0 + 4));
#pragma unroll
                for (int j = 0; j < 4; j++) {
                    o[j]     = (short)ar1_f2b(a[j]);
                    o[4 + j] = (short)ar1_f2b(c[j]);
                }
            } else {
                o = *((const bf16x8*)(xw + i0));
            }
            *((bf16x8*)(xb + i0)) = o;
        }
    }
}

// per-partition -> contiguous CSR slice + indeg/offs/dinv (self-scans gbase)
// + scales this partition's xb rows by dinv (so the layer-1 gather is an
// unweighted sum, same as layers 2/3).
__global__ __launch_bounds__(256)
void ar1_csr(const unsigned int* __restrict__ pairs, const int* __restrict__ gcur,
             int* __restrict__ csr, int* __restrict__ indeg,
             int* __restrict__ offs, float* __restrict__ dinv,
             unsigned short* __restrict__ xb) {
    __shared__ int ncnt[512], pre[512], cur[512], psum[16], red[256];
    int p = (int)blockIdx.x, tid = (int)threadIdx.x;
    red[tid] = (tid < p && tid < NPART) ? gcur[tid] : 0;
    __syncthreads();
    for (int o = 128; o > 0; o >>= 1) {
        if (tid < o) red[tid] += red[tid + o];
        __syncthreads();
    }
    int gbase = red[0];
    int cntE = gcur[p];
    if (cntE > PSLOT) cntE = PSLOT;
    for (int i = tid; i < 512; i += 256) ncnt[i] = 0;
    __syncthreads();
    const unsigned int* pp = pairs + (size_t)p * PSLOT;
    for (int i = tid; i < cntE; i += 256) atomicAdd(&ncnt[pp[i] >> 17], 1);
    __syncthreads();
    if (tid < 16) {
        int s = 0;
        for (int j = tid * 32; j < tid * 32 + 32; j++) { pre[j] = s; s += ncnt[j]; }
        psum[tid] = s;
    }
    __syncthreads();
    if (tid == 0) {
        int s = 0;
        for (int j = 0; j < 16; j++) { int t = psum[j]; psum[j] = s; s += t; }
    }
    __syncthreads();
    if (tid < 16)
        for (int j = tid * 32; j < tid * 32 + 32; j++) pre[j] += psum[tid];
    __syncthreads();
    for (int j = tid; j < 512; j += 256) {
        cur[j] = pre[j];
        int node = p * 512 + j;
        if (node < GN) {
            indeg[node] = ncnt[j];
            offs[node] = gbase + pre[j];
            dinv[node] = rsqrtf((float)(ncnt[j] + 1));   // +1: self loop
        }
    }
    __syncthreads();
    for (int i = tid; i < cntE; i += 256) {
        unsigned v = pp[i];
        int r = atomicAdd(&cur[v >> 17], 1);
        csr[gbase + r] = (int)(v & 0x1FFFFu);
    }
    // scale this partition's xb rows by dinv (ncnt stable in LDS)
    for (int i = tid; i < 512 * 8; i += 256) {
        int j = i >> 3, c = i & 7;
        int node = p * 512 + j;
        if (node < GN) {
            float sc = rsqrtf((float)(ncnt[j] + 1));
            bf16x8 v = *((bf16x8*)(xb + (size_t)node * 64 + c * 8));
#pragma unroll
            for (int jj = 0; jj < 8; jj++)
                v[jj] = (short)ar1_f2b(sc * ar1_b2f((unsigned short)v[jj]));
            *((bf16x8*)(xb + (size_t)node * 64 + c * 8)) = v;
        }
    }
}

// ---------------- fused agg64 + GEMM1 (64->96) ------------------------------
// 512 threads = 8 waves, 16 nodes/block: wave wv gathers nodes wv and wv+8
// as two independent interleaved chains (16-edge chunks, 2 rows in flight
// each). MFMA tiles 16-row all-valid. Epilogue pre-scales by dinv[row].
__global__ __launch_bounds__(512, 8)
void ar1_ag64g(const unsigned short* __restrict__ Xb, const int* __restrict__ offs,
               const int* __restrict__ indeg, const int* __restrict__ csr,
               const float* __restrict__ dinv,
               const unsigned short* __restrict__ Bp,
               const float* __restrict__ scale, const float* __restrict__ shift,
               unsigned short* __restrict__ C) {
    __shared__ unsigned short AL[16 * 72];
    int tid = (int)threadIdx.x, wv = tid >> 6, lane = tid & 63;
    int nb = (int)blockIdx.x * 16;
    int nodeA = nb + wv, nodeB = nb + wv + 8;
    int chunk = lane & 7, eslot = lane >> 3;
    float diA = dinv[nodeA], diB = dinv[nodeB];
    int offA = offs[nodeA], cntA = indeg[nodeA];
    int offB = offs[nodeB], cntB = indeg[nodeB];
    int cmax = cntA > cntB ? cntA : cntB;

    floatx2 aA[4], aB[4];
#pragma unroll
    for (int d = 0; d < 4; d++) { aA[d] = (floatx2){0.f, 0.f}; aB[d] = (floatx2){0.f, 0.f}; }

    for (int base = 0; base < cmax; base += 16) {
        int sA[2], sB[2];
#pragma unroll
        for (int k = 0; k < 2; k++) {
            int e = base + k * 8 + eslot;
            sA[k] = (e < cntA) ? csr[offA + e] : GN;   // row GN all zeros
            sB[k] = (e < cntB) ? csr[offB + e] : GN;
        }
        uintx4 hA[2], hB[2];
#pragma unroll
        for (int k = 0; k < 2; k++) {
            hA[k] = *((const uintx4*)(Xb + (size_t)sA[k] * 64 + chunk * 8));
            hB[k] = *((const uintx4*)(Xb + (size_t)sB[k] * 64 + chunk * 8));
        }
#pragma unroll
        for (int k = 0; k < 2; k++)
#pragma unroll
            for (int d = 0; d < 4; d++) {
                aA[d] += ar1_up2(hA[k][d]);
                aB[d] += ar1_up2(hB[k][d]);
            }
    }
#pragma unroll
    for (int d = 0; d < 4; d++)
#pragma unroll
        for (int c = 0; c < 2; c++) {
            aA[d][c] += __shfl_xor(aA[d][c], 8, 64);
            aA[d][c] += __shfl_xor(aA[d][c], 16, 64);
            aA[d][c] += __shfl_xor(aA[d][c], 32, 64);
            aB[d][c] += __shfl_xor(aB[d][c], 8, 64);
            aB[d][c] += __shfl_xor(aB[d][c], 16, 64);
            aB[d][c] += __shfl_xor(aB[d][c], 32, 64);
        }
    if (eslot == 0) {
        bf16x8 hsA = *((const bf16x8*)(Xb + (size_t)nodeA * 64 + chunk * 8));
        bf16x8 hsB = *((const bf16x8*)(Xb + (size_t)nodeB * 64 + chunk * 8));
        bf16x8 oA, oB;
#pragma unroll
        for (int j = 0; j < 8; j++) {
            oA[j] = (short)ar1_f2b(diA * (aA[j >> 1][j & 1] +
                                          ar1_b2f((unsigned short)hsA[j])));
            oB[j] = (short)ar1_f2b(diB * (aB[j >> 1][j & 1] +
                                          ar1_b2f((unsigned short)hsB[j])));
        }
        *((bf16x8*)(AL + (size_t)wv * 72 + chunk * 8)) = oA;
        *((bf16x8*)(AL + (size_t)(wv + 8) * 72 + chunk * 8)) = oB;
    }
    __syncthreads();

    if (wv < 6) {                       // GEMM: t = wv, K=64 (nch=2)
        int m = lane & 15, quad = lane >> 4, t = wv;
        floatx4 g = (floatx4){0.f, 0.f, 0.f, 0.f};
#pragma unroll
        for (int c = 0; c < 2; c++) {
            bf16x8 a = *((const bf16x8*)(AL + (size_t)m * 72 + c * 32 + quad * 8));
            bf16x8 bfr = *((const bf16x8*)(Bp + ((size_t)(t * 2 + c) * 64 + lane) * 8));
            g = __builtin_amdgcn_mfma_f32_16x16x32_bf16(a, bfr, g, 0, 0, 0);
        }
#pragma unroll
        for (int r = 0; r < 4; r++) {
            int row = nb + quad * 4 + r;
            int col = t * 16 + m;
            float v = g[r] * scale[col] + shift[col];
            C[(size_t)row * 96 + col] = ar1_f2b(dinv[row] * fmaxf(v, 0.f));
        }
    }
}

// ---------------- fused agg96 + GEMM2 (96->96) ------------------------------
// 8 waves, 16 nodes/block, 2 nodes per wave; 8-edge chunks (2 rows in
// flight per chain, 4 total). AL = di*(acc + H'[node]). Epilogue pre-scales.
__global__ __launch_bounds__(512, 8)
void ar1_ag96g(const unsigned short* __restrict__ H, const int* __restrict__ offs,
               const int* __restrict__ indeg, const int* __restrict__ csr,
               const float* __restrict__ dinv,
               const unsigned short* __restrict__ Bp,
               const float* __restrict__ scale, const float* __restrict__ shift,
               unsigned short* __restrict__ C) {
    __shared__ unsigned short AL[16 * 104];
    int tid = (int)threadIdx.x, wv = tid >> 6, lane = tid & 63;
    int nb = (int)blockIdx.x * 16;
    int nodeA = nb + wv, nodeB = nb + wv + 8;
    int chunk = lane % 12, eslot = lane / 12;
    float diA = dinv[nodeA], diB = dinv[nodeB];
    int offA = offs[nodeA], cntA = indeg[nodeA];
    int offB = offs[nodeB], cntB = indeg[nodeB];
    int cmax = cntA > cntB ? cntA : cntB;

    floatx2 aA[4], aB[4];
#pragma unroll
    for (int d = 0; d < 4; d++) { aA[d] = (floatx2){0.f, 0.f}; aB[d] = (floatx2){0.f, 0.f}; }

    if (lane < 48) {
        for (int base = 0; base < cmax; base += 8) {
            int sA[2], sB[2];
#pragma unroll
            for (int k = 0; k < 2; k++) {
                int e = base + k * 4 + eslot;
                sA[k] = (e < cntA) ? csr[offA + e] : GN;   // row GN all zeros
                sB[k] = (e < cntB) ? csr[offB + e] : GN;
            }
            uintx4 hA[2], hB[2];
#pragma unroll
            for (int k = 0; k < 2; k++) {
                hA[k] = *((const uintx4*)(H + (size_t)sA[k] * 96 + chunk * 8));
                hB[k] = *((const uintx4*)(H + (size_t)sB[k] * 96 + chunk * 8));
            }
#pragma unroll
            for (int k = 0; k < 2; k++)
#pragma unroll
                for (int d = 0; d < 4; d++) {
                    aA[d] += ar1_up2(hA[k][d]);
                    aB[d] += ar1_up2(hB[k][d]);
                }
        }
    }
#pragma unroll
    for (int d = 0; d < 4; d++)
#pragma unroll
        for (int c = 0; c < 2; c++) {
            float x1 = __shfl(aA[d][c], lane + 12, 64);
            float x2 = __shfl(aA[d][c], lane + 24, 64);
            float x3 = __shfl(aA[d][c], lane + 36, 64);
            aA[d][c] += x1 + x2 + x3;
            float y1 = __shfl(aB[d][c], lane + 12, 64);
            float y2 = __shfl(aB[d][c], lane + 24, 64);
            float y3 = __shfl(aB[d][c], lane + 36, 64);
            aB[d][c] += y1 + y2 + y3;
        }
    if (lane < 12) {
        bf16x8 hsA = *((const bf16x8*)(H + (size_t)nodeA * 96 + chunk * 8));
        bf16x8 hsB = *((const bf16x8*)(H + (size_t)nodeB * 96 + chunk * 8));
        bf16x8 oA, oB;
#pragma unroll
        for (int j = 0; j < 8; j++) {
            oA[j] = (short)ar1_f2b(diA * (aA[j >> 1][j & 1] +
                                          ar1_b2f((unsigned short)hsA[j])));
            oB[j] = (short)ar1_f2b(diB * (aB[j >> 1][j & 1] +
                                          ar1_b2f((unsigned short)hsB[j])));
        }
        *((bf16x8*)(AL + (size_t)wv * 104 + chunk * 8)) = oA;
        *((bf16x8*)(AL + (size_t)(wv + 8) * 104 + chunk * 8)) = oB;
    }
    __syncthreads();

    if (wv < 6) {                       // GEMM: t = wv, K=96 (nch=3)
        int m = lane & 15, quad = lane >> 4, t = wv;
        floatx4 g = (floatx4){0.f, 0.f, 0.f, 0.f};
#pragma unroll
        for (int c = 0; c < 3; c++) {
            bf16x8 a = *((const bf16x8*)(AL + (size_t)m * 104 + c * 32 + quad * 8));
            bf16x8 bfr = *((const bf16x8*)(Bp + ((size_t)(t * 3 + c) * 64 + lane) * 8));
            g = __builtin_amdgcn_mfma_f32_16x16x32_bf16(a, bfr, g, 0, 0, 0);
        }
#pragma unroll
        for (int r = 0; r < 4; r++) {
            int row = nb + quad * 4 + r;
            int col = t * 16 + m;
            float v = g[r] * scale[col] + shift[col];
            C[(size_t)row * 96 + col] = ar1_f2b(dinv[row] * fmaxf(v, 0.f));
        }
    }
}

// ---------------- fused agg96 + GEMM3 + full MLP -> d_out -------------------
// Gather identical to ar1_ag96g (2 nodes/wave); barriered phases:
// GEMM3 (waves 0-5), L1 (8 waves x 2 tiles), L2 (8 waves), L3 (0-3),
// L4 (wave 0 -> out, 16 rows).
__global__ __launch_bounds__(512, 8)
void ar1_agmlp(const unsigned short* __restrict__ H, const int* __restrict__ offs,
               const int* __restrict__ indeg, const int* __restrict__ csr,
               const float* __restrict__ dinv,
               const unsigned short* __restrict__ b2w,
               const float* __restrict__ sc3, const float* __restrict__ sh3,
               const unsigned short* __restrict__ b3,
               const unsigned short* __restrict__ b4,
               const unsigned short* __restrict__ b5,
               const unsigned short* __restrict__ b6,
               const float* __restrict__ lb0, const float* __restrict__ lb1,
               const float* __restrict__ lb2, const float* __restrict__ lb3,
               void* __restrict__ out, const int* __restrict__ f32out) {
    __shared__ unsigned short AL[16 * 104];   // aggregate rows
    __shared__ unsigned short H0[16 * 104];   // gemm3 out (96 cols)
    __shared__ unsigned short H1[16 * 264];   // 256 cols
    __shared__ unsigned short H2[16 * 136];   // 128 cols
    __shared__ unsigned short H3[16 * 72];    // 64 cols
    int tid = (int)threadIdx.x, wv = tid >> 6, lane = tid & 63;
    int nb = (int)blockIdx.x * 16;
    int m = lane & 15, quad = lane >> 4;

    // ---- gather phase (2 nodes per wave, independent chains) ----
    {
        int nodeA = nb + wv, nodeB = nb + wv + 8;
        int chunk = lane % 12, eslot = lane / 12;
        float diA = dinv[nodeA], diB = dinv[nodeB];
        int offA = offs[nodeA], cntA = indeg[nodeA];
        int offB = offs[nodeB], cntB = indeg[nodeB];
        int cmax = cntA > cntB ? cntA : cntB;
        floatx2 aA[4], aB[4];
#pragma unroll
        for (int d = 0; d < 4; d++) { aA[d] = (floatx2){0.f, 0.f}; aB[d] = (floatx2){0.f, 0.f}; }
        if (lane < 48) {
            for (int base = 0; base < cmax; base += 8) {
                int sA[2], sB[2];
#pragma unroll
                for (int k = 0; k < 2; k++) {
                    int e = base + k * 4 + eslot;
                    sA[k] = (e < cntA) ? csr[offA + e] : GN;
                    sB[k] = (e < cntB) ? csr[offB + e] : GN;
                }
                uintx4 hA[2], hB[2];
#pragma unroll
                for (int k = 0; k < 2; k++) {
                    hA[k] = *((const uintx4*)(H + (size_t)sA[k] * 96 + chunk * 8));
                    hB[k] = *((const uintx4*)(H + (size_t)sB[k] * 96 + chunk * 8));
                }
#pragma unroll
                for (int k = 0; k < 2; k++)
#pragma unroll
                    for (int d = 0; d < 4; d++) {
                        aA[d] += ar1_up2(hA[k][d]);
                        aB[d] += ar1_up2(hB[k][d]);
                    }
            }
        }
#pragma unroll
        for (int d = 0; d < 4; d++)
#pragma unroll
            for (int c = 0; c < 2; c++) {
                float x1 = __shfl(aA[d][c], lane + 12, 64);
                float x2 = __shfl(aA[d][c], lane + 24, 64);
                float x3 = __shfl(aA[d][c], lane + 36, 64);
                aA[d][c] += x1 + x2 + x3;
                float y1 = __shfl(aB[d][c], lane + 12, 64);
                float y2 = __shfl(aB[d][c], lane + 24, 64);
                float y3 = __shfl(aB[d][c], lane + 36, 64);
                aB[d][c] += y1 + y2 + y3;
            }
        if (lane < 12) {
            bf16x8 hsA = *((const bf16x8*)(H + (size_t)nodeA * 96 + chunk * 8));
            bf16x8 hsB = *((const bf16x8*)(H + (size_t)nodeB * 96 + chunk * 8));
            bf16x8 oA, oB;
#pragma unroll
            for (int j = 0; j < 8; j++) {
                oA[j] = (short)ar1_f2b(diA * (aA[j >> 1][j & 1] +
                                              ar1_b2f((unsigned short)hsA[j])));
                oB[j] = (short)ar1_f2b(diB * (aB[j >> 1][j & 1] +
                                              ar1_b2f((unsigned short)hsB[j])));
            }
            *((bf16x8*)(AL + (size_t)wv * 104 + chunk * 8)) = oA;
            *((bf16x8*)(AL + (size_t)(wv + 8) * 104 + chunk * 8)) = oB;
        }
    }
    __syncthreads();

    // ---- GEMM3: 96 -> 96, affine+ReLU (waves 0-5) ----
    if (wv < 6) {
        int t = wv;
        floatx4 g = (floatx4){0.f, 0.f, 0.f, 0.f};
#pragma unroll
        for (int c = 0; c < 3; c++) {
            bf16x8 a = *((const bf16x8*)(AL + (size_t)m * 104 + c * 32 + quad * 8));
            bf16x8 bfr = *((const bf16x8*)(b2w + ((size_t)(t * 3 + c) * 64 + lane) * 8));
            g = __builtin_amdgcn_mfma_f32_16x16x32_bf16(a, bfr, g, 0, 0, 0);
        }
#pragma unroll
        for (int r = 0; r < 4; r++) {
            int col = t * 16 + m;
            float v = g[r] * sc3[col] + sh3[col];
            H0[(quad * 4 + r) * 104 + col] = ar1_f2b(fmaxf(v, 0.f));
        }
    }
    __syncthreads();

    // ---- MLP L1: 96 -> 256 (+lb0, ReLU) (8 waves x 2 tiles) ----
    {
#pragma unroll
        for (int tt = 0; tt < 2; tt++) {
            int t = wv + tt * 8;
            floatx4 g = (floatx4){0.f, 0.f, 0.f, 0.f};
#pragma unroll
            for (int c = 0; c < 3; c++) {
                bf16x8 a = *((const bf16x8*)(H0 + (size_t)m * 104 + c * 32 + quad * 8));
                bf16x8 bfr = *((const bf16x8*)(b3 + ((size_t)(t * 3 + c) * 64 + lane) * 8));
                g = __builtin_amdgcn_mfma_f32_16x16x32_bf16(a, bfr, g, 0, 0, 0);
            }
#pragma unroll
            for (int r = 0; r < 4; r++) {
                int col = t * 16 + m;
                H1[(quad * 4 + r) * 264 + col] = ar1_f2b(fmaxf(g[r] + lb0[col], 0.f));
            }
        }
    }
    __syncthreads();

    // ---- MLP L2: 256 -> 128 (+lb1, ReLU) (8 waves) ----
    {
        int t = wv;
        floatx4 g = (floatx4){0.f, 0.f, 0.f, 0.f};
#pragma unroll
        for (int c = 0; c < 8; c++) {
            bf16x8 a = *((const bf16x8*)(H1 + (size_t)m * 264 + c * 32 + quad * 8));
            bf16x8 bfr = *((const bf16x8*)(b4 + ((size_t)(t * 8 + c) * 64 + lane) * 8));
            g = __builtin_amdgcn_mfma_f32_16x16x32_bf16(a, bfr, g, 0, 0, 0);
        }
#pragma unroll
        for (int r = 0; r < 4; r++) {
            int col = t * 16 + m;
            H2[(quad * 4 + r) * 136 + col] = ar1_f2b(fmaxf(g[r] + lb1[col], 0.f));
        }
    }
    __syncthreads();

    // ---- MLP L3: 128 -> 64 (+lb2, ReLU) (waves 0-3) ----
    if (wv < 4) {
        int t = wv;
        floatx4 g = (floatx4){0.f, 0.f, 0.f, 0.f};
#pragma unroll
        for (int c = 0; c < 4; c++) {
            bf16x8 a = *((const bf16x8*)(H2 + (size_t)m * 136 + c * 32 + quad * 8));
            bf16x8 bfr = *((const bf16x8*)(b5 + ((size_t)(t * 4 + c) * 64 + lane) * 8));
            g = __builtin_amdgcn_mfma_f32_16x16x32_bf16(a, bfr, g, 0, 0, 0);
        }
#pragma unroll
        for (int r = 0; r < 4; r++) {
            int col = t * 16 + m;
            H3[(quad * 4 + r) * 72 + col] = ar1_f2b(fmaxf(g[r] + lb2[col], 0.f));
        }
    }
    __syncthreads();

    // ---- MLP L4: 64 -> 8 (+lb3) (wave 0 -> out, 16 rows) ----
    if (wv == 0) {
        floatx4 g = (floatx4){0.f, 0.f, 0.f, 0.f};
#pragma unroll
        for (int c = 0; c < 2; c++) {
            bf16x8 a = *((const bf16x8*)(H3 + (size_t)m * 72 + c * 32 + quad * 8));
            bf16x8 bfr = *((const bf16x8*)(b6 + ((size_t)c * 64 + lane) * 8));
            g = __builtin_amdgcn_mfma_f32_16x16x32_bf16(a, bfr, g, 0, 0, 0);
        }
        int wf32 = f32out[0];
#pragma unroll
        for (int r = 0; r < 4; r++) {
            int row = nb + quad * 4 + r;
            if (m < 8) {
                float v = g[r] + lb3[m];
                if (wf32) ((float*)out)[(size_t)row * 8 + m] = v;
                else ((unsigned short*)out)[(size_t)row * 8 + m] = ar1_f2b(v);
            }
        }
    }
}

extern "C" void kernel_launch(void* const* d_in, const int* in_sizes, int n_in,
                              void* d_out, int out_size, void* d_ws, size_t ws_size,
                              hipStream_t stream) {
    (void)in_sizes; (void)n_in; (void)out_size;

    // workspace layout (+1 zero row on xb/bufA/bufB; dinv padded for [GN])
    char* p = (char*)d_ws;
    unsigned short* bufA = (unsigned short*)p; p += (size_t)(GN + 1) * 96 * 2;
    unsigned short* bufB = (unsigned short*)p; p += (size_t)(GN + 1) * 96 * 2;
    unsigned short* xb   = (unsigned short*)p; p += (size_t)(GN + 1) * 64 * 2;
    unsigned int* pairs = (unsigned int*)p; p += (size_t)NPART * PSLOT * 4; // 3.6 MB
    int* indeg  = (int*)p;    p += (size_t)GN * 4;
    int* offs   = (int*)p;    p += (size_t)GN * 4;
    float* dinv = (float*)p;  p += (size_t)GN * 4 + 64;
    int* csr    = (int*)p;    p += (size_t)GE * 4;
    int* gcur   = (int*)p;    p += 1024;
    int* flagI  = (int*)p;    p += 1024;
    int* flagF  = (int*)p;    p += 1024;
    unsigned short* bpArena = (unsigned short*)p; p += 91136 * 2;  // packed W
    float* fArena = (float*)p; p += 2048 * 4;                      // small fp32
    size_t need = (size_t)(p - (char*)d_ws);
    if (ws_size < need) {
        hipMemsetAsync(d_out, 0x41, (size_t)GN * 8 * 2, stream);  // marker 12.06
        return;
    }

    // packed-weight arena offsets (shorts): w1,w2,w3,lw1,lw2,lw3,lw4
    unsigned short* bp[7];
    int bpn[7] = {6144, 9216, 9216, 24576, 32768, 8192, 1024};
    {
        unsigned short* q = bpArena;
        for (int i = 0; i < 7; i++) { bp[i] = q; q += bpn[i]; }
    }

    // small fp32 arena: lb1(256),lb2(128),lb3(64),lb4(8), 6 x 96 scale/shift
    float* lb[4]; float* ss[6];
    {
        float* q = fArena;
        int ln[4] = {256, 128, 64, 8};
        for (int i = 0; i < 4; i++) { lb[i] = q; q += ln[i]; }
        for (int i = 0; i < 6; i++) { ss[i] = q; q += 96; }
    }

    const int* ei = (const int*)d_in[1];
    const unsigned short* xw = (const unsigned short*)d_in[0];

    // graph build + weight prep + X->bf16: memset, merged kernel, csr
    hipMemsetAsync(gcur, 0, NPART * 4, stream);
    {
        PackAll pa;
        int wsrc[7] = {2, 6, 10, 14, 16, 18, 20};
        int Ks[7] = {64, 96, 96, 96, 256, 128, 64};
        int Ms[7] = {96, 96, 96, 256, 128, 64, 8};
        int cum = 0;
        for (int i = 0; i < 7; i++) {
            pa.src[i] = d_in[wsrc[i]]; pa.dst[i] = bp[i];
            pa.K[i] = Ks[i]; pa.M[i] = Ms[i];
            pa.start[i] = cum;
            cum += (Ms[i] + 15) / 16 * (Ks[i] / 32);
        }
        pa.start[7] = cum;   // 178
        SmallCvt sc;
        int lsrc[4] = {15, 17, 19, 21};
        int ln[4] = {256, 128, 64, 8};
        for (int i = 0; i < 4; i++) { sc.src[i] = d_in[lsrc[i]]; sc.dst[i] = lb[i]; sc.n[i] = ln[i]; }
        int gsrc[9] = {3, 4, 5, 7, 8, 9, 11, 12, 13};
        for (int i = 0; i < 9; i++) sc.gb[i] = d_in[gsrc[i]];
        for (int i = 0; i < 6; i++) sc.ss[i] = ss[i];
        Arthur1_16458314678864_kernel<<<2000, 256, 0, stream>>>(
            pa, sc, ei, xw, flagI, flagF, gcur, pairs, xb, bufA, bufB, dinv);
    }
    ar1_csr<<<NPART, 256, 0, stream>>>(pairs, gcur, csr, indeg, offs, dinv, xb);

    const int FB = GN / 16;           // 3125 blocks, 512 threads, 16 nodes

    // GCN layers 1,2 fused agg+GEMM; layer 3 + GEMM3 + MLP in one kernel
    ar1_ag64g<<<FB, 512, 0, stream>>>(xb, offs, indeg, csr, dinv,
                                      bp[0], ss[0], ss[1], bufA);
    ar1_ag96g<<<FB, 512, 0, stream>>>(bufA, offs, indeg, csr, dinv,
                                      bp[1], ss[2], ss[3], bufB);
    ar1_agmlp<<<FB, 512, 0, stream>>>(bufB, offs, indeg, csr, dinv,
                                      bp[2], ss[4], ss[5],
                                      bp[3], bp[4], bp[5], bp[6],
                                      lb[0], lb[1], lb[2], lb[3], d_out, flagF);
}

// Round 11
// 277.351 us; speedup vs baseline: 1.0512x; 1.0512x over previous
//
#include <hip/hip_runtime.h>

// GCN(3 layers) + MLP(4 layers), N=50000, E=800000, out = N x 8 bf16.
// NOTE: do NOT include <hip/hip_bf16.h> — breaks this harness's build.
// Manual bf16 ushort ops. Dtype runtime-detection: flagI/flagF.
//
// R24/R26 best (277.7 µs): fused agg+GEMM, 16-edge chunks, dinv-pre-scaled
// rows (all gathers unweighted sums), agmlp 61.2 µs @ 1.14 TB/s effective.
// R25/R27/R28/R29/R30: SEVEN in-structure attempts to raise gather
// concurrency all failed: MFMA phases + launch_bounds pin ~32 VGPR (spills
// beyond), and block barriers park waves (~30 lines in flight/CU vs ~130
// issuable). The fused structure is boxed in from both sides.
// R31 (this round): SPLIT gather from compute.
//  - ar1_gat64/ar1_gat96: pure gather kernels (256 thr = 4 waves = 4 nodes,
//    NO barriers, NO MFMA -> no AGPR pressure, proven 28-VGPR footprint,
//    32 waves/CU all gathering continuously). Write aggregated row
//    di*(acc+self) to global agg buffer.
//  - ar1_gem1/ar1_gem2: stream 16 contiguous agg rows -> LDS, 1 barrier,
//    proven MFMA GEMM + BN/ReLU + dinv pre-scale epilogue.
//  - ar1_mlp: R26 agmlp with gather replaced by streaming agg load.

#define GN 50000
#define GE 800000
#define NPART 98        // partitions of 512 dst nodes
#define PSLOT 9216      // slab capacity per partition (mean 8163, +11 sigma)
#define CHK 2048        // edges per block in pass 1

typedef __attribute__((ext_vector_type(8))) short bf16x8;
typedef __attribute__((ext_vector_type(4))) float floatx4;
typedef __attribute__((ext_vector_type(2))) float floatx2;
typedef __attribute__((ext_vector_type(4))) unsigned int uintx4;

__device__ __forceinline__ float ar1_b2f(unsigned short h) {
    return __uint_as_float(((unsigned)h) << 16);
}
__device__ __forceinline__ unsigned short ar1_f2b(float f) {
    unsigned u = __float_as_uint(f);
    u = u + 0x7FFFu + ((u >> 16) & 1u);   // round-to-nearest-even
    return (unsigned short)(u >> 16);
}
// unpack one dword (2 packed bf16) -> f32x2 {lo, hi}
__device__ __forceinline__ floatx2 ar1_up2(unsigned w) {
    floatx2 t;
    t[0] = __uint_as_float(w << 16);
    t[1] = __uint_as_float(w & 0xFFFF0000u);
    return t;
}

// wave-parallel detectors (4 loads + butterfly; every wave gets the answer)
__device__ __forceinline__ int ar1_det64(const int* ei) {
    int l = (int)threadIdx.x & 63;
    int nz = 0;
#pragma unroll
    for (int k = 0; k < 4; k++)
        nz += (ei[2 * (l + 64 * k) + 1] != 0) ? 1 : 0;
#pragma unroll
    for (int o = 1; o < 64; o <<= 1)
        nz += __shfl_xor(nz, o, 64);
    return (nz < 8) ? 1 : 0;                 // 1 => int64
}
__device__ __forceinline__ int ar1_detf32(const unsigned short* xw) {
    int l = (int)threadIdx.x & 63;
    int c = 0;
#pragma unroll
    for (int k = 0; k < 4; k++) {
        unsigned short w = xw[2 * (l + 64 * k)];
        int ex = (w >> 7) & 0xFF;
        if (w == 0 || (ex >= 90 && ex <= 150)) c++;
    }
#pragma unroll
    for (int o = 1; o < 64; o <<= 1)
        c += __shfl_xor(c, o, 64);
    return (c > 200) ? 0 : 1;                // 1 => fp32
}

struct PackAll {
    const void* src[7];
    unsigned short* dst[7];
    int K[7], M[7], start[8];
};
struct SmallCvt {
    const void* src[4];   // lb1, lb2, lb3, lb4
    float* dst[4];
    int n[4];
    const void* gb[9];    // b1,g1,be1, b2,g2,be2, b3,g3,be3
    float* ss[6];         // scale1,shift1, ...
};

// merged prep (carries harness kernel name), grid = 391 + 45 + 1 + 1563 = 2000:
//  b<391: edge partition pass (self-detected is64); needs gcur pre-zeroed.
//  b<436: pack 4 MFMA B-fragments each (self-detected flagF).
//  b==436: small cvt + BN fold; zero-rows + dinv[GN]; writes flagI/flagF.
//  b>=437: X -> Xb bf16 conversion (8 elems/thread, streaming).
__global__ __launch_bounds__(256)
void Arthur1_16458314678864_kernel(PackAll pa, SmallCvt sc,
                                   const int* __restrict__ ei,
                                   const unsigned short* __restrict__ xw,
                                   int* flagI, int* flagF,
                                   int* __restrict__ gcur,
                                   unsigned int* __restrict__ pairs,
                                   unsigned short* __restrict__ xb,
                                   unsigned short* __restrict__ bufA,
                                   unsigned short* __restrict__ bufB,
                                   float* __restrict__ dinvp) {
    int b = (int)blockIdx.x;
    int tid = (int)threadIdx.x;
    if (b < 391) {
        __shared__ int cnt[NPART], base[NPART], cur[NPART];
        for (int i = tid; i < NPART; i += 256) { cnt[i] = 0; cur[i] = 0; }
        int is64 = ar1_det64(ei);
        __syncthreads();
        int e0 = b * CHK;
        unsigned pk[8]; int q[8];
#pragma unroll
        for (int k = 0; k < 8; k++) {
            int e = e0 + k * 256 + tid;
            q[k] = -1; pk[k] = 0;
            if (e < GE) {
                int s = is64 ? ei[2 * e] : ei[e];
                int d = is64 ? ei[2 * (GE + e)] : ei[GE + e];
                if ((unsigned)s < (unsigned)GN && (unsigned)d < (unsigned)GN) {
                    int qq = d >> 9;
                    q[k] = qq;
                    pk[k] = (unsigned)s | ((unsigned)(d & 511) << 17);
                    atomicAdd(&cnt[qq], 1);
                }
            }
        }
        __syncthreads();
        for (int i = tid; i < NPART; i += 256)
            base[i] = (cnt[i] > 0) ? atomicAdd(&gcur[i], cnt[i]) : 0;
        __syncthreads();
#pragma unroll
        for (int k = 0; k < 8; k++) {
            if (q[k] >= 0) {
                int r = base[q[k]] + atomicAdd(&cur[q[k]], 1);
                if (r < PSLOT) pairs[(size_t)q[k] * PSLOT + r] = pk[k];
            }
        }
    } else if (b < 436) {
        int f = ar1_detf32(xw);
        int frag_g = (b - 391) * 4 + (tid >> 6);
        if (frag_g >= 178) return;
        int w = 0;
        while (w < 6 && frag_g >= pa.start[w + 1]) w++;
        int frag = frag_g - pa.start[w];
        int K = pa.K[w], M = pa.M[w];
        int lane = tid & 63;
        int nch = K >> 5;
        int t = frag / nch, c = frag - t * nch;
        int n = t * 16 + (lane & 15);
        int k0 = c * 32 + (lane >> 4) * 8;
        unsigned short* o = pa.dst[w] + ((size_t)frag * 64 + lane) * 8;
        for (int j = 0; j < 8; j++) {
            unsigned short v = 0;
            if (n < M) {
                int idx = (k0 + j) * M + n;
                v = f ? ar1_f2b(((const float*)pa.src[w])[idx])
                      : ((const unsigned short*)pa.src[w])[idx];
            }
            o[j] = v;
        }
    } else if (b == 436) {
        int f = ar1_detf32(xw);
        int i64 = ar1_det64(ei);
        if (tid == 0) { flagI[0] = i64; flagF[0] = f; dinvp[GN] = 0.f; }
        // zero pad rows (row GN) for the zero-row gather-padding trick
        if (tid < 96) {
            bufA[(size_t)GN * 96 + tid] = 0;
            bufB[(size_t)GN * 96 + tid] = 0;
        }
        if (tid >= 96 && tid < 160) xb[(size_t)GN * 64 + (tid - 96)] = 0;
        const float C = 0.9999950000374997f;   // 1/sqrt(1+1e-5)
        for (int s = 0; s < 4; s++) {
            for (int i = tid; i < sc.n[s]; i += 256) {
                float v = f ? ((const float*)sc.src[s])[i]
                            : ar1_b2f(((const unsigned short*)sc.src[s])[i]);
                sc.dst[s][i] = v;
            }
        }
        for (int k = 0; k < 3; k++) {
            for (int i = tid; i < 96; i += 256) {
                float bb, g, be;
                if (f) {
                    bb = ((const float*)sc.gb[3 * k + 0])[i];
                    g  = ((const float*)sc.gb[3 * k + 1])[i];
                    be = ((const float*)sc.gb[3 * k + 2])[i];
                } else {
                    bb = ar1_b2f(((const unsigned short*)sc.gb[3 * k + 0])[i]);
                    g  = ar1_b2f(((const unsigned short*)sc.gb[3 * k + 1])[i]);
                    be = ar1_b2f(((const unsigned short*)sc.gb[3 * k + 2])[i]);
                }
                sc.ss[2 * k + 0][i] = C * g;
                sc.ss[2 * k + 1][i] = bb * C * g + be;
            }
        }
    } else {
        // X -> bf16 rows (one cache line per row for the layer-1 gather).
        // (dinv scaling is applied later by ar1_csr once degrees are known.)
        int f = ar1_detf32(xw);
        size_t t = (size_t)(b - 437) * 256 + (size_t)tid;
        size_t i0 = t * 8;
        if (i0 < (size_t)GN * 64) {
            bf16x8 o;
            if (f) {
                const float* xf = (const float*)xw;
                floatx4 a = *((const floatx4*)(xf + i0));
                floatx4 c = *((const floatx4*)(xf + i0 + 4));
#pragma unroll
                for (int j = 0; j < 4; j++) {
                    o[j]     = (short)ar1_f2b(a[j]);
                    o[4 + j] = (short)ar1_f2b(c[j]);
                }
            } else {
                o = *((const bf16x8*)(xw + i0));
            }
            *((bf16x8*)(xb + i0)) = o;
        }
    }
}

// per-partition -> contiguous CSR slice + indeg/offs/dinv (self-scans gbase)
// + scales this partition's xb rows by dinv (so all gathers are plain sums).
__global__ __launch_bounds__(256)
void ar1_csr(const unsigned int* __restrict__ pairs, const int* __restrict__ gcur,
             int* __restrict__ csr, int* __restrict__ indeg,
             int* __restrict__ offs, float* __restrict__ dinv,
             unsigned short* __restrict__ xb) {
    __shared__ int ncnt[512], pre[512], cur[512], psum[16], red[256];
    int p = (int)blockIdx.x, tid = (int)threadIdx.x;
    red[tid] = (tid < p && tid < NPART) ? gcur[tid] : 0;
    __syncthreads();
    for (int o = 128; o > 0; o >>= 1) {
        if (tid < o) red[tid] += red[tid + o];
        __syncthreads();
    }
    int gbase = red[0];
    int cntE = gcur[p];
    if (cntE > PSLOT) cntE = PSLOT;
    for (int i = tid; i < 512; i += 256) ncnt[i] = 0;
    __syncthreads();
    const unsigned int* pp = pairs + (size_t)p * PSLOT;
    for (int i = tid; i < cntE; i += 256) atomicAdd(&ncnt[pp[i] >> 17], 1);
    __syncthreads();
    if (tid < 16) {
        int s = 0;
        for (int j = tid * 32; j < tid * 32 + 32; j++) { pre[j] = s; s += ncnt[j]; }
        psum[tid] = s;
    }
    __syncthreads();
    if (tid == 0) {
        int s = 0;
        for (int j = 0; j < 16; j++) { int t = psum[j]; psum[j] = s; s += t; }
    }
    __syncthreads();
    if (tid < 16)
        for (int j = tid * 32; j < tid * 32 + 32; j++) pre[j] += psum[tid];
    __syncthreads();
    for (int j = tid; j < 512; j += 256) {
        cur[j] = pre[j];
        int node = p * 512 + j;
        if (node < GN) {
            indeg[node] = ncnt[j];
            offs[node] = gbase + pre[j];
            dinv[node] = rsqrtf((float)(ncnt[j] + 1));   // +1: self loop
        }
    }
    __syncthreads();
    for (int i = tid; i < cntE; i += 256) {
        unsigned v = pp[i];
        int r = atomicAdd(&cur[v >> 17], 1);
        csr[gbase + r] = (int)(v & 0x1FFFFu);
    }
    // scale this partition's xb rows by dinv (ncnt stable in LDS)
    for (int i = tid; i < 512 * 8; i += 256) {
        int j = i >> 3, c = i & 7;
        int node = p * 512 + j;
        if (node < GN) {
            float sc = rsqrtf((float)(ncnt[j] + 1));
            bf16x8 v = *((bf16x8*)(xb + (size_t)node * 64 + c * 8));
#pragma unroll
            for (int jj = 0; jj < 8; jj++)
                v[jj] = (short)ar1_f2b(sc * ar1_b2f((unsigned short)v[jj]));
            *((bf16x8*)(xb + (size_t)node * 64 + c * 8)) = v;
        }
    }
}

// ---------------- pure gather, 64-wide rows ---------------------------------
// 256 thr = 4 waves = 4 nodes; NO barriers, NO MFMA. R24 footprint.
// Agg[node] = di * (sum_{s in nbrs} Xb[s] + Xb[node])   (Xb pre-scaled)
__global__ __launch_bounds__(256, 8)
void ar1_gat64(const unsigned short* __restrict__ Xb, const int* __restrict__ offs,
               const int* __restrict__ indeg, const int* __restrict__ csr,
               const float* __restrict__ dinv,
               unsigned short* __restrict__ Agg) {
    int tid = (int)threadIdx.x, wv = tid >> 6, lane = tid & 63;
    int node = (int)blockIdx.x * 4 + wv;     // 12500 * 4 = GN
    int chunk = lane & 7, eslot = lane >> 3;
    float di = dinv[node];
    int off = offs[node], cnt = indeg[node];

    floatx2 acc2[4];
#pragma unroll
    for (int d = 0; d < 4; d++) acc2[d] = (floatx2){0.f, 0.f};

    for (int base = 0; base < cnt; base += 16) {
        int ss[2];
#pragma unroll
        for (int k = 0; k < 2; k++) {
            int e = base + k * 8 + eslot;
            ss[k] = (e < cnt) ? csr[off + e] : GN;   // row GN all zeros
        }
        uintx4 hh[2];
#pragma unroll
        for (int k = 0; k < 2; k++)
            hh[k] = *((const uintx4*)(Xb + (size_t)ss[k] * 64 + chunk * 8));
#pragma unroll
        for (int k = 0; k < 2; k++)
#pragma unroll
            for (int d = 0; d < 4; d++)
                acc2[d] += ar1_up2(hh[k][d]);
    }
#pragma unroll
    for (int d = 0; d < 4; d++)
#pragma unroll
        for (int c = 0; c < 2; c++) {
            acc2[d][c] += __shfl_xor(acc2[d][c], 8, 64);
            acc2[d][c] += __shfl_xor(acc2[d][c], 16, 64);
            acc2[d][c] += __shfl_xor(acc2[d][c], 32, 64);
        }
    if (eslot == 0) {
        bf16x8 h = *((const bf16x8*)(Xb + (size_t)node * 64 + chunk * 8));
        bf16x8 o;
#pragma unroll
        for (int j = 0; j < 8; j++)
            o[j] = (short)ar1_f2b(di * (acc2[j >> 1][j & 1] +
                                        ar1_b2f((unsigned short)h[j])));
        *((bf16x8*)(Agg + (size_t)node * 64 + chunk * 8)) = o;
    }
}

// ---------------- pure gather, 96-wide rows ---------------------------------
// 256 thr = 4 waves = 4 nodes; NO barriers, NO MFMA. R26 footprint.
__global__ __launch_bounds__(256, 8)
void ar1_gat96(const unsigned short* __restrict__ H, const int* __restrict__ offs,
               const int* __restrict__ indeg, const int* __restrict__ csr,
               const float* __restrict__ dinv,
               unsigned short* __restrict__ Agg) {
    int tid = (int)threadIdx.x, wv = tid >> 6, lane = tid & 63;
    int node = (int)blockIdx.x * 4 + wv;
    int chunk = lane % 12, eslot = lane / 12;
    float di = dinv[node];
    int off = offs[node], cnt = indeg[node];

    floatx2 acc2[4];
#pragma unroll
    for (int d = 0; d < 4; d++) acc2[d] = (floatx2){0.f, 0.f};

    if (lane < 48) {
        for (int base = 0; base < cnt; base += 16) {
            int ss[4];
#pragma unroll
            for (int k = 0; k < 4; k++) {
                int e = base + k * 4 + eslot;
                ss[k] = (e < cnt) ? csr[off + e] : GN;   // row GN all zeros
            }
            uintx4 hh[4];
#pragma unroll
            for (int k = 0; k < 4; k++)
                hh[k] = *((const uintx4*)(H + (size_t)ss[k] * 96 + chunk * 8));
#pragma unroll
            for (int k = 0; k < 4; k++)
#pragma unroll
                for (int d = 0; d < 4; d++)
                    acc2[d] += ar1_up2(hh[k][d]);
        }
    }
#pragma unroll
    for (int d = 0; d < 4; d++)
#pragma unroll
        for (int c = 0; c < 2; c++) {
            float a1 = __shfl(acc2[d][c], lane + 12, 64);
            float a2 = __shfl(acc2[d][c], lane + 24, 64);
            float a3 = __shfl(acc2[d][c], lane + 36, 64);
            acc2[d][c] += a1 + a2 + a3;
        }
    if (lane < 12) {
        bf16x8 hs = *((const bf16x8*)(H + (size_t)node * 96 + chunk * 8));
        bf16x8 o;
#pragma unroll
        for (int j = 0; j < 8; j++)
            o[j] = (short)ar1_f2b(di * (acc2[j >> 1][j & 1] +
                                        ar1_b2f((unsigned short)hs[j])));
        *((bf16x8*)(Agg + (size_t)node * 96 + chunk * 8)) = o;
    }
}

// ---------------- GEMM1: 64 -> 96, BN+ReLU, dinv pre-scale ------------------
// 512 thr, 16 nodes/block, 3125 blocks. Streams 16 contiguous agg rows
// (2 KB) into LDS, one barrier, MFMA by waves 0-5.
__global__ __launch_bounds__(512, 8)
void ar1_gem1(const unsigned int* __restrict__ Agg, const float* __restrict__ dinv,
              const unsigned short* __restrict__ Bp,
              const float* __restrict__ scale, const float* __restrict__ shift,
              unsigned short* __restrict__ C) {
    __shared__ unsigned short AL[16 * 72];
    int tid = (int)threadIdx.x;
    int nb = (int)blockIdx.x * 16;
    {
        int row = tid >> 5, dw = tid & 31;           // 512 dwords exactly
        ((unsigned*)AL)[row * 36 + dw] = Agg[(size_t)nb * 32 + tid];
    }
    __syncthreads();

    int wv = tid >> 6, lane = tid & 63;
    if (wv < 6) {                       // GEMM: t = wv, K=64 (nch=2)
        int m = lane & 15, quad = lane >> 4, t = wv;
        floatx4 g = (floatx4){0.f, 0.f, 0.f, 0.f};
#pragma unroll
        for (int c = 0; c < 2; c++) {
            bf16x8 a = *((const bf16x8*)(AL + (size_t)m * 72 + c * 32 + quad * 8));
            bf16x8 bfr = *((const bf16x8*)(Bp + ((size_t)(t * 2 + c) * 64 + lane) * 8));
            g = __builtin_amdgcn_mfma_f32_16x16x32_bf16(a, bfr, g, 0, 0, 0);
        }
#pragma unroll
        for (int r = 0; r < 4; r++) {
            int row = nb + quad * 4 + r;
            int col = t * 16 + m;
            float v = g[r] * scale[col] + shift[col];
            C[(size_t)row * 96 + col] = ar1_f2b(dinv[row] * fmaxf(v, 0.f));
        }
    }
}

// ---------------- GEMM2: 96 -> 96, BN+ReLU, dinv pre-scale ------------------
__global__ __launch_bounds__(512, 8)
void ar1_gem2(const unsigned int* __restrict__ Agg, const float* __restrict__ dinv,
              const unsigned short* __restrict__ Bp,
              const float* __restrict__ scale, const float* __restrict__ shift,
              unsigned short* __restrict__ C) {
    __shared__ unsigned short AL[16 * 104];
    int tid = (int)threadIdx.x;
    int nb = (int)blockIdx.x * 16;
    for (int i = tid; i < 768; i += 512) {           // 16 rows x 48 dwords
        int row = i / 48, dw = i - row * 48;
        ((unsigned*)AL)[row * 52 + dw] = Agg[(size_t)nb * 48 + i];
    }
    __syncthreads();

    int wv = tid >> 6, lane = tid & 63;
    if (wv < 6) {                       // GEMM: t = wv, K=96 (nch=3)
        int m = lane & 15, quad = lane >> 4, t = wv;
        floatx4 g = (floatx4){0.f, 0.f, 0.f, 0.f};
#pragma unroll
        for (int c = 0; c < 3; c++) {
            bf16x8 a = *((const bf16x8*)(AL + (size_t)m * 104 + c * 32 + quad * 8));
            bf16x8 bfr = *((const bf16x8*)(Bp + ((size_t)(t * 3 + c) * 64 + lane) * 8));
            g = __builtin_amdgcn_mfma_f32_16x16x32_bf16(a, bfr, g, 0, 0, 0);
        }
#pragma unroll
        for (int r = 0; r < 4; r++) {
            int row = nb + quad * 4 + r;
            int col = t * 16 + m;
            float v = g[r] * scale[col] + shift[col];
            C[(size_t)row * 96 + col] = ar1_f2b(dinv[row] * fmaxf(v, 0.f));
        }
    }
}

// ---------------- GEMM3 + full MLP -> d_out ---------------------------------
// R26 agmlp with the gather replaced by a streaming agg load. 1024 thr,
// 16 nodes/block; barriered phases: GEMM3 (waves 0-5), L1 (all 16),
// L2 (0-7), L3 (0-3), L4 (wave 0 -> out).
__global__ __launch_bounds__(1024, 8)
void ar1_mlp(const unsigned int* __restrict__ Agg,
             const unsigned short* __restrict__ b2w,
             const float* __restrict__ sc3, const float* __restrict__ sh3,
             const unsigned short* __restrict__ b3,
             const unsigned short* __restrict__ b4,
             const unsigned short* __restrict__ b5,
             const unsigned short* __restrict__ b6,
             const float* __restrict__ lb0, const float* __restrict__ lb1,
             const float* __restrict__ lb2, const float* __restrict__ lb3,
             void* __restrict__ out, const int* __restrict__ f32out) {
    __shared__ unsigned short AL[16 * 104];   // aggregate rows
    __shared__ unsigned short H0[16 * 104];   // gemm3 out (96 cols)
    __shared__ unsigned short H1[16 * 264];   // 256 cols
    __shared__ unsigned short H2[16 * 136];   // 128 cols
    __shared__ unsigned short H3[16 * 72];    // 64 cols
    int tid = (int)threadIdx.x, wv = tid >> 6, lane = tid & 63;
    int nb = (int)blockIdx.x * 16;
    int m = lane & 15, quad = lane >> 4;

    if (tid < 768) {                          // 16 rows x 48 dwords
        int row = tid / 48, dw = tid - row * 48;
        ((unsigned*)AL)[row * 52 + dw] = Agg[(size_t)nb * 48 + tid];
    }
    __syncthreads();

    // ---- GEMM3: 96 -> 96, affine+ReLU (waves 0-5) ----
    if (wv < 6) {
        int t = wv;
        floatx4 g = (floatx4){0.f, 0.f, 0.f, 0.f};
#pragma unroll
        for (int c = 0; c < 3; c++) {
            bf16x8 a = *((const bf16x8*)(AL + (size_t)m * 104 + c * 32 + quad * 8));
            bf16x8 bfr = *((const bf16x8*)(b2w + ((size_t)(t * 3 + c) * 64 + lane) * 8));
            g = __builtin_amdgcn_mfma_f32_16x16x32_bf16(a, bfr, g, 0, 0, 0);
        }
#pragma unroll
        for (int r = 0; r < 4; r++) {
            int col = t * 16 + m;
            float v = g[r] * sc3[col] + sh3[col];
            H0[(quad * 4 + r) * 104 + col] = ar1_f2b(fmaxf(v, 0.f));
        }
    }
    __syncthreads();

    // ---- MLP L1: 96 -> 256 (+lb0, ReLU) (all 16 waves) ----
    {
        int t = wv;
        floatx4 g = (floatx4){0.f, 0.f, 0.f, 0.f};
#pragma unroll
        for (int c = 0; c < 3; c++) {
            bf16x8 a = *((const bf16x8*)(H0 + (size_t)m * 104 + c * 32 + quad * 8));
            bf16x8 bfr = *((const bf16x8*)(b3 + ((size_t)(t * 3 + c) * 64 + lane) * 8));
            g = __builtin_amdgcn_mfma_f32_16x16x32_bf16(a, bfr, g, 0, 0, 0);
        }
#pragma unroll
        for (int r = 0; r < 4; r++) {
            int col = t * 16 + m;
            H1[(quad * 4 + r) * 264 + col] = ar1_f2b(fmaxf(g[r] + lb0[col], 0.f));
        }
    }
    __syncthreads();

    // ---- MLP L2: 256 -> 128 (+lb1, ReLU) (waves 0-7) ----
    if (wv < 8) {
        int t = wv;
        floatx4 g = (floatx4){0.f, 0.f, 0.f, 0.f};
#pragma unroll
        for (int c = 0; c < 8; c++) {
            bf16x8 a = *((const bf16x8*)(H1 + (size_t)m * 264 + c * 32 + quad * 8));
            bf16x8 bfr = *((const bf16x8*)(b4 + ((size_t)(t * 8 + c) * 64 + lane) * 8));
            g = __builtin_amdgcn_mfma_f32_16x16x32_bf16(a, bfr, g, 0, 0, 0);
        }
#pragma unroll
        for (int r = 0; r < 4; r++) {
            int col = t * 16 + m;
            H2[(quad * 4 + r) * 136 + col] = ar1_f2b(fmaxf(g[r] + lb1[col], 0.f));
        }
    }
    __syncthreads();

    // ---- MLP L3: 128 -> 64 (+lb2, ReLU) (waves 0-3) ----
    if (wv < 4) {
        int t = wv;
        floatx4 g = (floatx4){0.f, 0.f, 0.f, 0.f};
#pragma unroll
        for (int c = 0; c < 4; c++) {
            bf16x8 a = *((const bf16x8*)(H2 + (size_t)m * 136 + c * 32 + quad * 8));
            bf16x8 bfr = *((const bf16x8*)(b5 + ((size_t)(t * 4 + c) * 64 + lane) * 8));
            g = __builtin_amdgcn_mfma_f32_16x16x32_bf16(a, bfr, g, 0, 0, 0);
        }
#pragma unroll
        for (int r = 0; r < 4; r++) {
            int col = t * 16 + m;
            H3[(quad * 4 + r) * 72 + col] = ar1_f2b(fmaxf(g[r] + lb2[col], 0.f));
        }
    }
    __syncthreads();

    // ---- MLP L4: 64 -> 8 (+lb3) (wave 0 -> out) ----
    if (wv == 0) {
        floatx4 g = (floatx4){0.f, 0.f, 0.f, 0.f};
#pragma unroll
        for (int c = 0; c < 2; c++) {
            bf16x8 a = *((const bf16x8*)(H3 + (size_t)m * 72 + c * 32 + quad * 8));
            bf16x8 bfr = *((const bf16x8*)(b6 + ((size_t)c * 64 + lane) * 8));
            g = __builtin_amdgcn_mfma_f32_16x16x32_bf16(a, bfr, g, 0, 0, 0);
        }
        int wf32 = f32out[0];
#pragma unroll
        for (int r = 0; r < 4; r++) {
            int row = nb + quad * 4 + r;
            if (m < 8) {
                float v = g[r] + lb3[m];
                if (wf32) ((float*)out)[(size_t)row * 8 + m] = v;
                else ((unsigned short*)out)[(size_t)row * 8 + m] = ar1_f2b(v);
            }
        }
    }
}

extern "C" void kernel_launch(void* const* d_in, const int* in_sizes, int n_in,
                              void* d_out, int out_size, void* d_ws, size_t ws_size,
                              hipStream_t stream) {
    (void)in_sizes; (void)n_in; (void)out_size;

    // workspace layout (+1 zero row on xb/bufA/bufB; dinv padded for [GN])
    char* p = (char*)d_ws;
    unsigned short* bufA = (unsigned short*)p; p += (size_t)(GN + 1) * 96 * 2;
    unsigned short* bufB = (unsigned short*)p; p += (size_t)(GN + 1) * 96 * 2;
    unsigned short* xb   = (unsigned short*)p; p += (size_t)(GN + 1) * 64 * 2;
    unsigned short* agg64 = (unsigned short*)p; p += (size_t)GN * 64 * 2;  // 6.4 MB
    unsigned short* agg96 = (unsigned short*)p; p += (size_t)GN * 96 * 2;  // 9.6 MB
    unsigned int* pairs = (unsigned int*)p; p += (size_t)NPART * PSLOT * 4; // 3.6 MB
    int* indeg  = (int*)p;    p += (size_t)GN * 4;
    int* offs   = (int*)p;    p += (size_t)GN * 4;
    float* dinv = (float*)p;  p += (size_t)GN * 4 + 64;
    int* csr    = (int*)p;    p += (size_t)GE * 4;
    int* gcur   = (int*)p;    p += 1024;
    int* flagI  = (int*)p;    p += 1024;
    int* flagF  = (int*)p;    p += 1024;
    unsigned short* bpArena = (unsigned short*)p; p += 91136 * 2;  // packed W
    float* fArena = (float*)p; p += 2048 * 4;                      // small fp32
    size_t need = (size_t)(p - (char*)d_ws);
    if (ws_size < need) {
        hipMemsetAsync(d_out, 0x41, (size_t)GN * 8 * 2, stream);  // marker 12.06
        return;
    }

    // packed-weight arena offsets (shorts): w1,w2,w3,lw1,lw2,lw3,lw4
    unsigned short* bp[7];
    int bpn[7] = {6144, 9216, 9216, 24576, 32768, 8192, 1024};
    {
        unsigned short* q = bpArena;
        for (int i = 0; i < 7; i++) { bp[i] = q; q += bpn[i]; }
    }

    // small fp32 arena: lb1(256),lb2(128),lb3(64),lb4(8), 6 x 96 scale/shift
    float* lb[4]; float* ss[6];
    {
        float* q = fArena;
        int ln[4] = {256, 128, 64, 8};
        for (int i = 0; i < 4; i++) { lb[i] = q; q += ln[i]; }
        for (int i = 0; i < 6; i++) { ss[i] = q; q += 96; }
    }

    const int* ei = (const int*)d_in[1];
    const unsigned short* xw = (const unsigned short*)d_in[0];

    // graph build + weight prep + X->bf16: memset, merged kernel, csr
    hipMemsetAsync(gcur, 0, NPART * 4, stream);
    {
        PackAll pa;
        int wsrc[7] = {2, 6, 10, 14, 16, 18, 20};
        int Ks[7] = {64, 96, 96, 96, 256, 128, 64};
        int Ms[7] = {96, 96, 96, 256, 128, 64, 8};
        int cum = 0;
        for (int i = 0; i < 7; i++) {
            pa.src[i] = d_in[wsrc[i]]; pa.dst[i] = bp[i];
            pa.K[i] = Ks[i]; pa.M[i] = Ms[i];
            pa.start[i] = cum;
            cum += (Ms[i] + 15) / 16 * (Ks[i] / 32);
        }
        pa.start[7] = cum;   // 178
        SmallCvt sc;
        int lsrc[4] = {15, 17, 19, 21};
        int ln[4] = {256, 128, 64, 8};
        for (int i = 0; i < 4; i++) { sc.src[i] = d_in[lsrc[i]]; sc.dst[i] = lb[i]; sc.n[i] = ln[i]; }
        int gsrc[9] = {3, 4, 5, 7, 8, 9, 11, 12, 13};
        for (int i = 0; i < 9; i++) sc.gb[i] = d_in[gsrc[i]];
        for (int i = 0; i < 6; i++) sc.ss[i] = ss[i];
        Arthur1_16458314678864_kernel<<<2000, 256, 0, stream>>>(
            pa, sc, ei, xw, flagI, flagF, gcur, pairs, xb, bufA, bufB, dinv);
    }
    ar1_csr<<<NPART, 256, 0, stream>>>(pairs, gcur, csr, indeg, offs, dinv, xb);

    const int GB = GN / 4;            // 12500 gather blocks (256 thr)
    const int CB = GN / 16;           // 3125 compute blocks

    // layer 1: gather(xb) -> agg64; GEMM1 -> bufA (pre-scaled)
    ar1_gat64<<<GB, 256, 0, stream>>>(xb, offs, indeg, csr, dinv, agg64);
    ar1_gem1<<<CB, 512, 0, stream>>>((const unsigned*)agg64, dinv,
                                     bp[0], ss[0], ss[1], bufA);
    // layer 2: gather(bufA) -> agg96; GEMM2 -> bufB (pre-scaled)
    ar1_gat96<<<GB, 256, 0, stream>>>(bufA, offs, indeg, csr, dinv, agg96);
    ar1_gem2<<<CB, 512, 0, stream>>>((const unsigned*)agg96, dinv,
                                     bp[1], ss[2], ss[3], bufB);
    // layer 3: gather(bufB) -> agg96 (reuse); GEMM3 + MLP -> out
    ar1_gat96<<<GB, 256, 0, stream>>>(bufB, offs, indeg, csr, dinv, agg96);
    ar1_mlp<<<CB, 1024, 0, stream>>>((const unsigned*)agg96,
                                     bp[2], ss[4], ss[5],
                                     bp[3], bp[4], bp[5], bp[6],
                                     lb[0], lb[1], lb[2], lb[3], d_out, flagF);
}